// Round 10
// baseline (167.722 us; speedup 1.0000x reference)
//
#include <hip/hip_runtime.h>
#include <math.h>

#define SEQ 512
#define FDIM 64
#define D 8
#define NT 512
#define NQUAD 64           // row quads per block; quad owns rows {quad + u*64}
#define NE 8               // t-eighths
#define TE 64              // t-steps per eighth

__global__ __launch_bounds__(NT, 4) void hybrid_attn_kernel(
    const float* __restrict__ state,    // [B,S,F]
    const float* __restrict__ proj_w,   // [F,D]
    const float* __restrict__ proj_b,   // [D]
    const float* __restrict__ rotation, // [D,D]
    const float* __restrict__ entangle, // [D,D]
    const float* __restrict__ w1,       // [D,32]
    const float* __restrict__ b1,       // [32]
    const float* __restrict__ w2,       // [32,16]
    const float* __restrict__ b2,       // [16]
    const float* __restrict__ w3,       // [16,1]
    const float* __restrict__ b3,       // [1]
    float* __restrict__ out)            // [B,S]
{
    // ~43 KB LDS -> 2 blocks/CU = 16 waves/CU. No merge buffer (shfl butterfly).
    __shared__ __align__(16) float s_proj[SEQ * D];   // 16 KB (V)
    __shared__ __align__(16) float s_k[SEQ * D];      // 16 KB
    __shared__ __align__(16) float s_q[256 * D];      // 8 KB (this block's rows)
    __shared__ __align__(16) float s_pw[FDIM * D];    // 2 KB
    __shared__ float s_rot[D * D];
    __shared__ float s_ent[D * D];
    __shared__ float s_pb[D];
    __shared__ float s_w1[D * 32];
    __shared__ float s_b1[32];
    __shared__ float s_w2[32 * 16];
    __shared__ float s_b2[16];
    __shared__ float s_w3[16];
    __shared__ float s_b3[1];

    const int bb   = blockIdx.x;
    const int b    = bb >> 1;      // batch
    const int half = bb & 1;       // which 256 q-rows this block owns
    const int tid  = threadIdx.x;

    // ---- stage small weights into LDS ----
    if (tid < FDIM * D) s_pw[tid] = proj_w[tid];
    if (tid < D * D) {
        s_rot[tid] = rotation[tid];
        s_ent[tid] = entangle[tid];
    }
    if (tid < D)       s_pb[tid] = proj_b[tid];
    if (tid < D * 32)  s_w1[tid] = w1[tid];
    if (tid < 32)      s_b1[tid] = b1[tid];
    if (tid < 32 * 16) s_w2[tid] = w2[tid];
    if (tid < 16) { s_b2[tid] = b2[tid]; s_w3[tid] = w3[tid]; }
    if (tid == 0)      s_b3[0] = b3[0];
    __syncthreads();

    // ---- phase 1 (verified): one thread per row; proj,k -> LDS; own q -> LDS ----
    {
        const int r = tid;
        float pj[D];
        #pragma unroll
        for (int j = 0; j < D; j++) pj[j] = s_pb[j];

        const float4* srp = (const float4*)(state + ((size_t)b * SEQ + r) * FDIM);
        #pragma unroll
        for (int c = 0; c < FDIM / 4; c++) {
            float4 v = srp[c];
            float vs[4] = {v.x, v.y, v.z, v.w};
            #pragma unroll
            for (int e = 0; e < 4; e++) {
                #pragma unroll
                for (int j = 0; j < D; j++) pj[j] += vs[e] * s_pw[(c * 4 + e) * D + j];
            }
        }

        const float QS = 0.35355339059327373f;  // 1/sqrt(8) folded into q
        float qv[D], kv[D];
        #pragma unroll
        for (int j = 0; j < D; j++) {
            float aq = 0.f, ak = 0.f;
            #pragma unroll
            for (int i = 0; i < D; i++) {
                aq += pj[i] * s_rot[i * D + j];
                ak += pj[i] * s_ent[i * D + j];
            }
            qv[j] = aq * QS;
            kv[j] = ak;
        }

        float4* dp = (float4*)(s_proj + r * D);
        dp[0] = make_float4(pj[0], pj[1], pj[2], pj[3]);
        dp[1] = make_float4(pj[4], pj[5], pj[6], pj[7]);
        float4* dk = (float4*)(s_k + r * D);
        dk[0] = make_float4(kv[0], kv[1], kv[2], kv[3]);
        dk[1] = make_float4(kv[4], kv[5], kv[6], kv[7]);
        if ((r >> 8) == half) {
            float4* dq = (float4*)(s_q + (r & 255) * D);
            dq[0] = make_float4(qv[0], qv[1], qv[2], qv[3]);
            dq[1] = make_float4(qv[4], qv[5], qv[6], qv[7]);
        }
    }
    __syncthreads();

    // ---- phase 2: 4 rows/thread (quad), t-eighth qt; sampled shared max ----
    const int quad = tid >> 3;          // 0..63
    const int qt   = tid & 7;           // t-eighth 0..7 (lane&7: butterfly-local)
    const int toff = qt * TE;

    float q[4][D];
    #pragma unroll
    for (int u = 0; u < 4; u++) {
        const float4* qp = (const float4*)(s_q + (quad + u * NQUAD) * D);
        float4 x0 = qp[0], x1 = qp[1];
        q[u][0]=x0.x; q[u][1]=x0.y; q[u][2]=x0.z; q[u][3]=x0.w;
        q[u][4]=x1.x; q[u][5]=x1.y; q[u][6]=x1.z; q[u][7]=x1.w;
    }

    // m-pass: sample every 4th t of own eighth (offset qt&3 spreads banks),
    // then butterfly-max across the 8 eighths -> m = max over 128 samples of all 512 t.
    float m[4] = {-1e30f, -1e30f, -1e30f, -1e30f};
    for (int i = 0; i < TE / 4; i++) {
        const int t = toff + 4 * i + (qt & 3);
        const float4* kt = (const float4*)(s_k + t * D);
        float4 k0 = kt[0], k1 = kt[1];
        #pragma unroll
        for (int u = 0; u < 4; u++) {
            float s = q[u][0]*k0.x + q[u][1]*k0.y + q[u][2]*k0.z + q[u][3]*k0.w
                    + q[u][4]*k1.x + q[u][5]*k1.y + q[u][6]*k1.z + q[u][7]*k1.w;
            m[u] = fmaxf(m[u], s);
        }
    }
    #pragma unroll
    for (int mask = 1; mask <= 4; mask <<= 1) {
        #pragma unroll
        for (int u = 0; u < 4; u++) m[u] = fmaxf(m[u], __shfl_xor(m[u], mask));
    }

    // main pass: shared m -> partials combine by plain summation.
    float l[4] = {0.f, 0.f, 0.f, 0.f};
    float acc[4][D];
    #pragma unroll
    for (int u = 0; u < 4; u++) {
        #pragma unroll
        for (int j = 0; j < D; j++) acc[u][j] = 0.f;
    }

    #pragma unroll 2
    for (int i = 0; i < TE; i++) {
        const int t = toff + ((i + qt) & (TE - 1));   // rotation: disjoint bank groups
        const float4* kt = (const float4*)(s_k + t * D);
        float4 k0 = kt[0], k1 = kt[1];
        float e[4];
        #pragma unroll
        for (int u = 0; u < 4; u++) {
            float s = -m[u]
                    + q[u][0]*k0.x + q[u][1]*k0.y + q[u][2]*k0.z + q[u][3]*k0.w
                    + q[u][4]*k1.x + q[u][5]*k1.y + q[u][6]*k1.z + q[u][7]*k1.w;
            e[u] = __expf(s);
            l[u] += e[u];
        }
        const float4* vt = (const float4*)(s_proj + t * D);
        float4 v0 = vt[0], v1 = vt[1];
        #pragma unroll
        for (int u = 0; u < 4; u++) {
            acc[u][0] += e[u]*v0.x; acc[u][1] += e[u]*v0.y;
            acc[u][2] += e[u]*v0.z; acc[u][3] += e[u]*v0.w;
            acc[u][4] += e[u]*v1.x; acc[u][5] += e[u]*v1.y;
            acc[u][6] += e[u]*v1.z; acc[u][7] += e[u]*v1.w;
        }
    }

    // butterfly-sum across the 8 eighths (same m everywhere -> exact plain sums)
    #pragma unroll
    for (int mask = 1; mask <= 4; mask <<= 1) {
        #pragma unroll
        for (int u = 0; u < 4; u++) {
            l[u] += __shfl_xor(l[u], mask);
            #pragma unroll
            for (int j = 0; j < D; j++) acc[u][j] += __shfl_xor(acc[u][j], mask);
        }
    }

    // ---- phase 3: each lane takes row u = qt&3 (static cndmask select), MLP ----
    const int u = qt & 3;
    float li = (u == 0) ? l[0] : (u == 1) ? l[1] : (u == 2) ? l[2] : l[3];
    float attn[D];
    #pragma unroll
    for (int j = 0; j < D; j++)
        attn[j] = (u == 0) ? acc[0][j] : (u == 1) ? acc[1][j]
                : (u == 2) ? acc[2][j] : acc[3][j];
    const float inv_l = 1.0f / li;
    #pragma unroll
    for (int j = 0; j < D; j++) attn[j] *= inv_l;

    float h1[32];
    #pragma unroll
    for (int j = 0; j < 32; j++) {
        float a = s_b1[j];
        #pragma unroll
        for (int i = 0; i < D; i++) a += attn[i] * s_w1[i * 32 + j];
        h1[j] = fmaxf(a, 0.f);
    }
    float h2[16];
    #pragma unroll
    for (int j = 0; j < 16; j++) {
        float a = s_b2[j];
        #pragma unroll
        for (int i = 0; i < 32; i++) a += h1[i] * s_w2[i * 16 + j];
        h2[j] = fmaxf(a, 0.f);
    }
    float o = s_b3[0];
    #pragma unroll
    for (int i = 0; i < 16; i++) o += h2[i] * s_w3[i];

    if (qt < 4)
        out[(size_t)b * SEQ + half * 256 + quad + u * NQUAD] = o;
}

extern "C" void kernel_launch(void* const* d_in, const int* in_sizes, int n_in,
                              void* d_out, int out_size, void* d_ws, size_t ws_size,
                              hipStream_t stream) {
    const float* state    = (const float*)d_in[0];
    const float* proj_w   = (const float*)d_in[1];
    const float* proj_b   = (const float*)d_in[2];
    const float* rotation = (const float*)d_in[3];
    const float* entangle = (const float*)d_in[4];
    const float* w1       = (const float*)d_in[5];
    const float* b1       = (const float*)d_in[6];
    const float* w2       = (const float*)d_in[7];
    const float* b2       = (const float*)d_in[8];
    const float* w3       = (const float*)d_in[9];
    const float* b3       = (const float*)d_in[10];
    float* out = (float*)d_out;

    const int B = in_sizes[0] / (SEQ * FDIM);  // 256
    hybrid_attn_kernel<<<B * 2, NT, 0, stream>>>(
        state, proj_w, proj_b, rotation, entangle,
        w1, b1, w2, b2, w3, b3, out);
}

// Round 11
// 144.090 us; speedup vs baseline: 1.1640x; 1.1640x over previous
//
#include <hip/hip_runtime.h>
#include <math.h>

#define SEQ 512
#define FDIM 64
#define D 8
#define NT 512
#define NPAIR 128          // row pairs per block (rows p and p+128 of the block's half)
#define NQ 4               // t-quarters (wave-uniform: qt = tid>>7)
#define TQ (SEQ / NQ)      // 128 t-steps per quarter

typedef float v2f __attribute__((ext_vector_type(2)));

__global__ __launch_bounds__(NT, 4) void hybrid_attn_kernel(
    const float* __restrict__ state,    // [B,S,F]
    const float* __restrict__ proj_w,   // [F,D]
    const float* __restrict__ proj_b,   // [D]
    const float* __restrict__ rotation, // [D,D]
    const float* __restrict__ entangle, // [D,D]
    const float* __restrict__ w1,       // [D,32]
    const float* __restrict__ b1,       // [32]
    const float* __restrict__ w2,       // [32,16]
    const float* __restrict__ b2,       // [16]
    const float* __restrict__ w3,       // [16,1]
    const float* __restrict__ b3,       // [1]
    float* __restrict__ out)            // [B,S]
{
    // ~78 KB LDS -> 2 blocks/CU = 16 waves/CU.
    __shared__ __align__(16) float s_proj[SEQ * D];          // 16 KB (V)
    __shared__ __align__(16) float s_k[SEQ * D];             // 16 KB
    __shared__ __align__(16) float s_q[256 * D];             // 8 KB (reused as s_attn)
    __shared__ __align__(16) float s_mrg[(NQ - 1) * NPAIR * 20]; // 30 KB
    __shared__ __align__(16) float s_mm[NQ * NPAIR * 2];     // 4 KB (per-quarter sampled maxes)
    __shared__ __align__(16) float s_pw[FDIM * D];           // 2 KB
    __shared__ float s_rot[D * D];
    __shared__ float s_ent[D * D];
    __shared__ float s_pb[D];
    __shared__ float s_w1[D * 32];
    __shared__ float s_b1[32];
    __shared__ float s_w2[32 * 16];
    __shared__ float s_b2[16];
    __shared__ float s_w3[16];
    __shared__ float s_b3[1];

    const int bb   = blockIdx.x;
    const int b    = bb >> 1;      // batch
    const int half = bb & 1;       // which 256 q-rows this block owns
    const int tid  = threadIdx.x;

    // ---- stage small weights into LDS ----
    if (tid < FDIM * D) s_pw[tid] = proj_w[tid];
    if (tid < D * D) {
        s_rot[tid] = rotation[tid];
        s_ent[tid] = entangle[tid];
    }
    if (tid < D)       s_pb[tid] = proj_b[tid];
    if (tid < D * 32)  s_w1[tid] = w1[tid];
    if (tid < 32)      s_b1[tid] = b1[tid];
    if (tid < 32 * 16) s_w2[tid] = w2[tid];
    if (tid < 16) { s_b2[tid] = b2[tid]; s_w3[tid] = w3[tid]; }
    if (tid == 0)      s_b3[0] = b3[0];
    __syncthreads();

    // ---- phase 1 (verified): one thread per row; proj,k -> LDS; own q -> LDS ----
    {
        const int r = tid;
        float pj[D];
        #pragma unroll
        for (int j = 0; j < D; j++) pj[j] = s_pb[j];

        const float4* srp = (const float4*)(state + ((size_t)b * SEQ + r) * FDIM);
        #pragma unroll
        for (int c = 0; c < FDIM / 4; c++) {
            float4 v = srp[c];
            float vs[4] = {v.x, v.y, v.z, v.w};
            #pragma unroll
            for (int e = 0; e < 4; e++) {
                #pragma unroll
                for (int j = 0; j < D; j++) pj[j] += vs[e] * s_pw[(c * 4 + e) * D + j];
            }
        }

        const float QS = 0.35355339059327373f;  // 1/sqrt(8) folded into q
        float qv[D], kv[D];
        #pragma unroll
        for (int j = 0; j < D; j++) {
            float aq = 0.f, ak = 0.f;
            #pragma unroll
            for (int i = 0; i < D; i++) {
                aq += pj[i] * s_rot[i * D + j];
                ak += pj[i] * s_ent[i * D + j];
            }
            qv[j] = aq * QS;
            kv[j] = ak;
        }

        float4* dp = (float4*)(s_proj + r * D);
        dp[0] = make_float4(pj[0], pj[1], pj[2], pj[3]);
        dp[1] = make_float4(pj[4], pj[5], pj[6], pj[7]);
        float4* dk = (float4*)(s_k + r * D);
        dk[0] = make_float4(kv[0], kv[1], kv[2], kv[3]);
        dk[1] = make_float4(kv[4], kv[5], kv[6], kv[7]);
        if ((r >> 8) == half) {
            float4* dq = (float4*)(s_q + (r & 255) * D);
            dq[0] = make_float4(qv[0], qv[1], qv[2], qv[3]);
            dq[1] = make_float4(qv[4], qv[5], qv[6], qv[7]);
        }
    }
    __syncthreads();

    // ---- phase 2: 2 rows/thread (pair p), t-quarter qt (wave-uniform) ----
    const int p    = tid & (NPAIR - 1);
    const int qt   = tid >> 7;
    const int toff = qt * TQ;

    v2f q0[4], q1[4];
    {
        const float4* qp = (const float4*)(s_q + p * D);
        float4 x0 = qp[0], x1 = qp[1];
        q0[0] = (v2f){x0.x, x0.y}; q0[1] = (v2f){x0.z, x0.w};
        q0[2] = (v2f){x1.x, x1.y}; q0[3] = (v2f){x1.z, x1.w};
        const float4* qp2 = (const float4*)(s_q + (p + NPAIR) * D);
        float4 y0 = qp2[0], y1 = qp2[1];
        q1[0] = (v2f){y0.x, y0.y}; q1[1] = (v2f){y0.z, y0.w};
        q1[2] = (v2f){y1.x, y1.y}; q1[3] = (v2f){y1.z, y1.w};
    }

    const float* kp = s_k    + toff * D;
    const float* vp = s_proj + toff * D;

    // m-pass: stride-4 sampled max over own quarter (32 samples), then global
    // per-row max via LDS exchange -> m from 128 samples of all 512 t.
    // (round-10-verified accuracy recipe; shared m -> plain-sum merge.)
    float m0 = -1e30f, m1 = -1e30f;
    for (int i = 0; i < TQ / 4; i++) {
        const float4* kt = (const float4*)(kp + (4 * i) * D);  // wave-uniform
        float4 ka = kt[0], kb = kt[1];
        v2f kk0 = (v2f){ka.x, ka.y}, kk1 = (v2f){ka.z, ka.w};
        v2f kk2 = (v2f){kb.x, kb.y}, kk3 = (v2f){kb.z, kb.w};
        v2f d0 = q0[0] * kk0; d0 = q0[1] * kk1 + d0;
        d0 = q0[2] * kk2 + d0; d0 = q0[3] * kk3 + d0;
        v2f d1 = q1[0] * kk0; d1 = q1[1] * kk1 + d1;
        d1 = q1[2] * kk2 + d1; d1 = q1[3] * kk3 + d1;
        m0 = fmaxf(m0, d0.x + d0.y);
        m1 = fmaxf(m1, d1.x + d1.y);
    }
    s_mm[(qt * NPAIR + p) * 2 + 0] = m0;
    s_mm[(qt * NPAIR + p) * 2 + 1] = m1;
    __syncthreads();
    #pragma unroll
    for (int w = 0; w < NQ; w++) {
        m0 = fmaxf(m0, s_mm[(w * NPAIR + p) * 2 + 0]);
        m1 = fmaxf(m1, s_mm[(w * NPAIR + p) * 2 + 1]);
    }
    const float nm0 = -m0, nm1 = -m1;

    // main pass: packed-fp32 dots + acc; shared m -> plain sums across quarters
    float l0 = 0.f, l1 = 0.f;
    v2f acc0[4] = {(v2f){0.f,0.f},(v2f){0.f,0.f},(v2f){0.f,0.f},(v2f){0.f,0.f}};
    v2f acc1[4] = {(v2f){0.f,0.f},(v2f){0.f,0.f},(v2f){0.f,0.f},(v2f){0.f,0.f}};
    #pragma unroll 2
    for (int t = 0; t < TQ; t++) {
        const float4* kt = (const float4*)(kp + t * D);  // wave-uniform -> broadcast
        float4 ka = kt[0], kb = kt[1];
        v2f kk0 = (v2f){ka.x, ka.y}, kk1 = (v2f){ka.z, ka.w};
        v2f kk2 = (v2f){kb.x, kb.y}, kk3 = (v2f){kb.z, kb.w};
        const float4* vt = (const float4*)(vp + t * D);
        float4 va = vt[0], vb = vt[1];
        v2f vv0 = (v2f){va.x, va.y}, vv1 = (v2f){va.z, va.w};
        v2f vv2 = (v2f){vb.x, vb.y}, vv3 = (v2f){vb.z, vb.w};

        v2f d0 = q0[0] * kk0; d0 = q0[1] * kk1 + d0;
        d0 = q0[2] * kk2 + d0; d0 = q0[3] * kk3 + d0;
        v2f d1 = q1[0] * kk0; d1 = q1[1] * kk1 + d1;
        d1 = q1[2] * kk2 + d1; d1 = q1[3] * kk3 + d1;

        float e0 = __expf(d0.x + d0.y + nm0);
        float e1 = __expf(d1.x + d1.y + nm1);
        l0 += e0; l1 += e1;
        v2f e0v = (v2f){e0, e0}, e1v = (v2f){e1, e1};
        acc0[0] = e0v * vv0 + acc0[0]; acc0[1] = e0v * vv1 + acc0[1];
        acc0[2] = e0v * vv2 + acc0[2]; acc0[3] = e0v * vv3 + acc0[3];
        acc1[0] = e1v * vv0 + acc1[0]; acc1[1] = e1v * vv1 + acc1[1];
        acc1[2] = e1v * vv2 + acc1[2]; acc1[3] = e1v * vv3 + acc1[3];
    }
    __syncthreads();

    // ---- quarters 1..3 publish partials; quarter 0 plain-sums (shared m) ----
    if (qt > 0) {
        float* dd = s_mrg + (size_t)((qt - 1) * NPAIR + p) * 20;
        ((float4*)dd)[0] = make_float4(acc0[0].x, acc0[0].y, acc0[1].x, acc0[1].y);
        ((float4*)dd)[1] = make_float4(acc0[2].x, acc0[2].y, acc0[3].x, acc0[3].y);
        ((float4*)dd)[2] = make_float4(acc1[0].x, acc1[0].y, acc1[1].x, acc1[1].y);
        ((float4*)dd)[3] = make_float4(acc1[2].x, acc1[2].y, acc1[3].x, acc1[3].y);
        dd[16] = l0;
        dd[17] = l1;
    }
    __syncthreads();

    float* const s_attn = s_q;   // q fully consumed; reuse as attn staging
    if (qt == 0) {
        #pragma unroll
        for (int w = 0; w < NQ - 1; w++) {
            const float* ss = s_mrg + (size_t)(w * NPAIR + p) * 20;
            float4 u0 = ((const float4*)ss)[0], u1 = ((const float4*)ss)[1];
            float4 u2 = ((const float4*)ss)[2], u3 = ((const float4*)ss)[3];
            acc0[0] += (v2f){u0.x, u0.y}; acc0[1] += (v2f){u0.z, u0.w};
            acc0[2] += (v2f){u1.x, u1.y}; acc0[3] += (v2f){u1.z, u1.w};
            acc1[0] += (v2f){u2.x, u2.y}; acc1[1] += (v2f){u2.z, u2.w};
            acc1[2] += (v2f){u3.x, u3.y}; acc1[3] += (v2f){u3.z, u3.w};
            l0 += ss[16];
            l1 += ss[17];
        }

        const float inv0 = 1.0f / l0;
        const float inv1 = 1.0f / l1;
        float4* d0 = (float4*)(s_attn + p * D);
        d0[0] = make_float4(acc0[0].x*inv0, acc0[0].y*inv0, acc0[1].x*inv0, acc0[1].y*inv0);
        d0[1] = make_float4(acc0[2].x*inv0, acc0[2].y*inv0, acc0[3].x*inv0, acc0[3].y*inv0);
        float4* d1 = (float4*)(s_attn + (p + NPAIR) * D);
        d1[0] = make_float4(acc1[0].x*inv1, acc1[0].y*inv1, acc1[1].x*inv1, acc1[1].y*inv1);
        d1[1] = make_float4(acc1[2].x*inv1, acc1[2].y*inv1, acc1[3].x*inv1, acc1[3].y*inv1);
    }
    __syncthreads();

    // ---- phase 3: MLP head d -> 32 -> 16 -> 1, one thread per owned row ----
    if (tid < 256) {
        const float4* ap = (const float4*)(s_attn + tid * D);
        float4 a0 = ap[0], a1 = ap[1];
        float attn[D] = {a0.x, a0.y, a0.z, a0.w, a1.x, a1.y, a1.z, a1.w};

        float h1[32];
        #pragma unroll
        for (int j = 0; j < 32; j++) {
            float a = s_b1[j];
            #pragma unroll
            for (int i = 0; i < D; i++) a += attn[i] * s_w1[i * 32 + j];
            h1[j] = fmaxf(a, 0.f);
        }
        float h2[16];
        #pragma unroll
        for (int j = 0; j < 16; j++) {
            float a = s_b2[j];
            #pragma unroll
            for (int i = 0; i < 32; i++) a += h1[i] * s_w2[i * 16 + j];
            h2[j] = fmaxf(a, 0.f);
        }
        float o = s_b3[0];
        #pragma unroll
        for (int i = 0; i < 16; i++) o += h2[i] * s_w3[i];

        out[(size_t)b * SEQ + half * 256 + tid] = o;
    }
}

extern "C" void kernel_launch(void* const* d_in, const int* in_sizes, int n_in,
                              void* d_out, int out_size, void* d_ws, size_t ws_size,
                              hipStream_t stream) {
    const float* state    = (const float*)d_in[0];
    const float* proj_w   = (const float*)d_in[1];
    const float* proj_b   = (const float*)d_in[2];
    const float* rotation = (const float*)d_in[3];
    const float* entangle = (const float*)d_in[4];
    const float* w1       = (const float*)d_in[5];
    const float* b1       = (const float*)d_in[6];
    const float* w2       = (const float*)d_in[7];
    const float* b2       = (const float*)d_in[8];
    const float* w3       = (const float*)d_in[9];
    const float* b3       = (const float*)d_in[10];
    float* out = (float*)d_out;

    const int B = in_sizes[0] / (SEQ * FDIM);  // 256
    hybrid_attn_kernel<<<B * 2, NT, 0, stream>>>(
        state, proj_w, proj_b, rotation, entangle,
        w1, b1, w2, b2, w3, b3, out);
}

// Round 12
// 131.198 us; speedup vs baseline: 1.2784x; 1.0983x over previous
//
#include <hip/hip_runtime.h>
#include <math.h>

#define SEQ 512
#define FDIM 64
#define D 8
#define NT 512
#define NP 128             // row quads per block: thread p owns rows {p+128u}
#define NQ 4               // t-quarters (wave-uniform: qt = tid>>7)
#define TQ (SEQ / NQ)      // 128 t-steps per quarter

typedef float v2f __attribute__((ext_vector_type(2)));

__global__ __launch_bounds__(NT, 2) void hybrid_attn_kernel(
    const float* __restrict__ state,    // [B,S,F]
    const float* __restrict__ proj_w,   // [F,D]
    const float* __restrict__ proj_b,   // [D]
    const float* __restrict__ rotation, // [D,D]
    const float* __restrict__ entangle, // [D,D]
    const float* __restrict__ w1,       // [D,32]
    const float* __restrict__ b1,       // [32]
    const float* __restrict__ w2,       // [32,16]
    const float* __restrict__ b2,       // [16]
    const float* __restrict__ w3,       // [16,1]
    const float* __restrict__ b3,       // [1]
    float* __restrict__ out)            // [B,S]
{
    // ~62 KB LDS. One block per batch: state read ONCE (HBM halved vs 2-block split).
    // s_pv: [0,4096) = proj/V, [4096,8192) = k; DEAD after main pass -> reused as
    // the 2-round merge buffer (3*128*18 = 6912 floats <= 8192).
    __shared__ __align__(16) float s_pv[2 * SEQ * D];   // 32 KB
    __shared__ __align__(16) float s_q[SEQ * D];        // 16 KB (reused as s_attn)
    __shared__ __align__(16) float s_mm[16 * NP];       // 8 KB  (sampled maxes, [u*4+qt][p])
    __shared__ __align__(16) float s_pw[FDIM * D];      // 2 KB
    __shared__ float s_rot[D * D];
    __shared__ float s_ent[D * D];
    __shared__ float s_pb[D];
    __shared__ float s_w1[D * 32];
    __shared__ float s_b1[32];
    __shared__ float s_w2[32 * 16];
    __shared__ float s_b2[16];
    __shared__ float s_w3[16];
    __shared__ float s_b3[1];

    float* const s_proj = s_pv;            // V
    float* const s_k    = s_pv + SEQ * D;

    const int b   = blockIdx.x;
    const int tid = threadIdx.x;

    // ---- stage small weights into LDS ----
    if (tid < FDIM * D) s_pw[tid] = proj_w[tid];
    if (tid < D * D) {
        s_rot[tid] = rotation[tid];
        s_ent[tid] = entangle[tid];
    }
    if (tid < D)       s_pb[tid] = proj_b[tid];
    if (tid < D * 32)  s_w1[tid] = w1[tid];
    if (tid < 32)      s_b1[tid] = b1[tid];
    if (tid < 32 * 16) s_w2[tid] = w2[tid];
    if (tid < 16) { s_b2[tid] = b2[tid]; s_w3[tid] = w3[tid]; }
    if (tid == 0)      s_b3[0] = b3[0];
    __syncthreads();

    // ---- phase 1 (verified): one thread per row; proj,k,q -> LDS ----
    {
        const int r = tid;
        float pj[D];
        #pragma unroll
        for (int j = 0; j < D; j++) pj[j] = s_pb[j];

        const float4* srp = (const float4*)(state + ((size_t)b * SEQ + r) * FDIM);
        #pragma unroll
        for (int c = 0; c < FDIM / 4; c++) {
            float4 v = srp[c];
            float vs[4] = {v.x, v.y, v.z, v.w};
            #pragma unroll
            for (int e = 0; e < 4; e++) {
                #pragma unroll
                for (int j = 0; j < D; j++) pj[j] += vs[e] * s_pw[(c * 4 + e) * D + j];
            }
        }

        const float QS = 0.35355339059327373f;  // 1/sqrt(8) folded into q
        float qv[D], kv[D];
        #pragma unroll
        for (int j = 0; j < D; j++) {
            float aq = 0.f, ak = 0.f;
            #pragma unroll
            for (int i = 0; i < D; i++) {
                aq += pj[i] * s_rot[i * D + j];
                ak += pj[i] * s_ent[i * D + j];
            }
            qv[j] = aq * QS;
            kv[j] = ak;
        }

        float4* dp = (float4*)(s_proj + r * D);
        dp[0] = make_float4(pj[0], pj[1], pj[2], pj[3]);
        dp[1] = make_float4(pj[4], pj[5], pj[6], pj[7]);
        float4* dk = (float4*)(s_k + r * D);
        dk[0] = make_float4(kv[0], kv[1], kv[2], kv[3]);
        dk[1] = make_float4(kv[4], kv[5], kv[6], kv[7]);
        float4* dq = (float4*)(s_q + r * D);
        dq[0] = make_float4(qv[0], qv[1], qv[2], qv[3]);
        dq[1] = make_float4(qv[4], qv[5], qv[6], qv[7]);
    }
    __syncthreads();

    // ---- phase 2: 4 rows/thread (p + 128u), t-quarter qt (wave-uniform) ----
    const int p    = tid & (NP - 1);
    const int qt   = tid >> 7;
    const int toff = qt * TQ;

    v2f q[4][4];
    #pragma unroll
    for (int u = 0; u < 4; u++) {
        const float4* qp = (const float4*)(s_q + (p + NP * u) * D);
        float4 x0 = qp[0], x1 = qp[1];
        q[u][0] = (v2f){x0.x, x0.y}; q[u][1] = (v2f){x0.z, x0.w};
        q[u][2] = (v2f){x1.x, x1.y}; q[u][3] = (v2f){x1.z, x1.w};
    }

    const float* kp = s_k    + toff * D;
    const float* vp = s_proj + toff * D;

    // m-pass: stride-4 sampled max over own quarter (32 samples/row), LDS
    // exchange -> global per-row m from 128 samples (round-10/11-verified recipe).
    float m[4] = {-1e30f, -1e30f, -1e30f, -1e30f};
    for (int i = 0; i < TQ / 4; i++) {
        const float4* kt = (const float4*)(kp + (4 * i) * D);  // wave-uniform
        float4 ka = kt[0], kb = kt[1];
        v2f kk0 = (v2f){ka.x, ka.y}, kk1 = (v2f){ka.z, ka.w};
        v2f kk2 = (v2f){kb.x, kb.y}, kk3 = (v2f){kb.z, kb.w};
        #pragma unroll
        for (int u = 0; u < 4; u++) {
            v2f d = q[u][0] * kk0; d = q[u][1] * kk1 + d;
            d = q[u][2] * kk2 + d; d = q[u][3] * kk3 + d;
            m[u] = fmaxf(m[u], d.x + d.y);
        }
    }
    #pragma unroll
    for (int u = 0; u < 4; u++) s_mm[(u * 4 + qt) * NP + p] = m[u];
    __syncthreads();
    float nm[4];
    #pragma unroll
    for (int u = 0; u < 4; u++) {
        float mu = s_mm[(u * 4 + 0) * NP + p];
        mu = fmaxf(mu, s_mm[(u * 4 + 1) * NP + p]);
        mu = fmaxf(mu, s_mm[(u * 4 + 2) * NP + p]);
        mu = fmaxf(mu, s_mm[(u * 4 + 3) * NP + p]);
        nm[u] = -mu;
    }

    // main pass: packed-fp32; nm folded into dot init; shared m -> plain sums.
    float l[4] = {0.f, 0.f, 0.f, 0.f};
    v2f acc[4][4];
    #pragma unroll
    for (int u = 0; u < 4; u++) {
        #pragma unroll
        for (int j = 0; j < 4; j++) acc[u][j] = (v2f){0.f, 0.f};
    }

    #pragma unroll 2
    for (int t = 0; t < TQ; t++) {
        const float4* kt = (const float4*)(kp + t * D);  // wave-uniform -> broadcast
        float4 ka = kt[0], kb = kt[1];
        v2f kk0 = (v2f){ka.x, ka.y}, kk1 = (v2f){ka.z, ka.w};
        v2f kk2 = (v2f){kb.x, kb.y}, kk3 = (v2f){kb.z, kb.w};
        const float4* vt = (const float4*)(vp + t * D);
        float4 va = vt[0], vb = vt[1];
        v2f vv0 = (v2f){va.x, va.y}, vv1 = (v2f){va.z, va.w};
        v2f vv2 = (v2f){vb.x, vb.y}, vv3 = (v2f){vb.z, vb.w};

        float e[4];
        #pragma unroll
        for (int u = 0; u < 4; u++) {
            v2f d = (v2f){nm[u], 0.f};
            d = q[u][0] * kk0 + d; d = q[u][1] * kk1 + d;
            d = q[u][2] * kk2 + d; d = q[u][3] * kk3 + d;
            e[u] = __expf(d.x + d.y);
            l[u] += e[u];
        }
        #pragma unroll
        for (int u = 0; u < 4; u++) {
            v2f ev = (v2f){e[u], e[u]};
            acc[u][0] = ev * vv0 + acc[u][0]; acc[u][1] = ev * vv1 + acc[u][1];
            acc[u][2] = ev * vv2 + acc[u][2]; acc[u][3] = ev * vv3 + acc[u][3];
        }
    }
    __syncthreads();   // all s_k/s_proj reads done -> s_pv reusable as merge buffer

    // ---- 2-round merge over s_pv (rows 0,1 then rows 2,3); stride 18 floats ----
    float* const s_mrg = s_pv;
    #pragma unroll
    for (int rnd = 0; rnd < 2; rnd++) {
        const int ua = 2 * rnd, ub = 2 * rnd + 1;
        if (qt > 0) {
            float* dd = s_mrg + (size_t)((qt - 1) * NP + p) * 18;
            ((float4*)dd)[0] = make_float4(acc[ua][0].x, acc[ua][0].y, acc[ua][1].x, acc[ua][1].y);
            ((float4*)dd)[1] = make_float4(acc[ua][2].x, acc[ua][2].y, acc[ua][3].x, acc[ua][3].y);
            ((float4*)dd)[2] = make_float4(acc[ub][0].x, acc[ub][0].y, acc[ub][1].x, acc[ub][1].y);
            ((float4*)dd)[3] = make_float4(acc[ub][2].x, acc[ub][2].y, acc[ub][3].x, acc[ub][3].y);
            dd[16] = l[ua];
            dd[17] = l[ub];
        }
        __syncthreads();
        if (qt == 0) {
            #pragma unroll
            for (int w = 0; w < NQ - 1; w++) {
                const float* ss = s_mrg + (size_t)(w * NP + p) * 18;
                float4 u0 = ((const float4*)ss)[0], u1 = ((const float4*)ss)[1];
                float4 u2 = ((const float4*)ss)[2], u3 = ((const float4*)ss)[3];
                acc[ua][0] += (v2f){u0.x, u0.y}; acc[ua][1] += (v2f){u0.z, u0.w};
                acc[ua][2] += (v2f){u1.x, u1.y}; acc[ua][3] += (v2f){u1.z, u1.w};
                acc[ub][0] += (v2f){u2.x, u2.y}; acc[ub][1] += (v2f){u2.z, u2.w};
                acc[ub][2] += (v2f){u3.x, u3.y}; acc[ub][3] += (v2f){u3.z, u3.w};
                l[ua] += ss[16];
                l[ub] += ss[17];
            }
        }
        __syncthreads();   // merge reads done before next round overwrites / attn staging
    }

    // ---- qt==0 normalizes + stages attn (s_q reused); then 512-thread MLP ----
    float* const s_attn = s_q;
    if (qt == 0) {
        #pragma unroll
        for (int u = 0; u < 4; u++) {
            const float inv = 1.0f / l[u];
            float4* dd = (float4*)(s_attn + (p + NP * u) * D);
            dd[0] = make_float4(acc[u][0].x*inv, acc[u][0].y*inv, acc[u][1].x*inv, acc[u][1].y*inv);
            dd[1] = make_float4(acc[u][2].x*inv, acc[u][2].y*inv, acc[u][3].x*inv, acc[u][3].y*inv);
        }
    }
    __syncthreads();

    // ---- phase 3: MLP head d -> 32 -> 16 -> 1, one thread per row ----
    {
        const float4* ap = (const float4*)(s_attn + tid * D);
        float4 a0 = ap[0], a1 = ap[1];
        float attn[D] = {a0.x, a0.y, a0.z, a0.w, a1.x, a1.y, a1.z, a1.w};

        float h1[32];
        #pragma unroll
        for (int j = 0; j < 32; j++) {
            float a = s_b1[j];
            #pragma unroll
            for (int i = 0; i < D; i++) a += attn[i] * s_w1[i * 32 + j];
            h1[j] = fmaxf(a, 0.f);
        }
        float h2[16];
        #pragma unroll
        for (int j = 0; j < 16; j++) {
            float a = s_b2[j];
            #pragma unroll
            for (int i = 0; i < 32; i++) a += h1[i] * s_w2[i * 16 + j];
            h2[j] = fmaxf(a, 0.f);
        }
        float o = s_b3[0];
        #pragma unroll
        for (int i = 0; i < 16; i++) o += h2[i] * s_w3[i];

        out[(size_t)b * SEQ + tid] = o;
    }
}

extern "C" void kernel_launch(void* const* d_in, const int* in_sizes, int n_in,
                              void* d_out, int out_size, void* d_ws, size_t ws_size,
                              hipStream_t stream) {
    const float* state    = (const float*)d_in[0];
    const float* proj_w   = (const float*)d_in[1];
    const float* proj_b   = (const float*)d_in[2];
    const float* rotation = (const float*)d_in[3];
    const float* entangle = (const float*)d_in[4];
    const float* w1       = (const float*)d_in[5];
    const float* b1       = (const float*)d_in[6];
    const float* w2       = (const float*)d_in[7];
    const float* b2       = (const float*)d_in[8];
    const float* w3       = (const float*)d_in[9];
    const float* b3       = (const float*)d_in[10];
    float* out = (float*)d_out;

    const int B = in_sizes[0] / (SEQ * FDIM);  // 256
    hybrid_attn_kernel<<<B, NT, 0, stream>>>(
        state, proj_w, proj_b, rotation, entangle,
        w1, b1, w2, b2, w3, b3, out);
}